// Round 1
// baseline (1160.084 us; speedup 1.0000x reference)
//
#include <hip/hip_runtime.h>
#include <math.h>

#define NEG_SLOPE 0.2f

__device__ __forceinline__ float lrelu(float z) { return z > 0.f ? z : NEG_SLOPE * z; }
__device__ __forceinline__ float elu1(float z)  { return z > 0.f ? z : (expf(z) - 1.f); }

// ---------------- CSR build ----------------

__global__ void k_hist(const int* __restrict__ ei, int E, int Et, int* __restrict__ deg) {
    int i = blockIdx.x * blockDim.x + threadIdx.x;
    if (i < Et) {
        int d = (i < E) ? ei[E + i] : (i - E);   // self-loop edges: dst = i - E
        atomicAdd(&deg[d], 1);
    }
}

// single-block exclusive scan over N elements -> offsets[N+1], cursor[N]
__global__ void k_scan(const int* __restrict__ deg, int N,
                       int* __restrict__ offsets, int* __restrict__ cursor) {
    __shared__ int sums[1024];
    int tid = threadIdx.x;
    int chunk = (N + 1023) / 1024;
    int lo = tid * chunk;
    int hi = min(lo + chunk, N);
    int s = 0;
    for (int i = lo; i < hi; i++) s += deg[i];
    sums[tid] = s;
    __syncthreads();
    for (int ofs = 1; ofs < 1024; ofs <<= 1) {
        int v = 0;
        if (tid >= ofs) v = sums[tid - ofs];
        __syncthreads();
        if (tid >= ofs) sums[tid] += v;
        __syncthreads();
    }
    int run = (tid == 0) ? 0 : sums[tid - 1];
    for (int i = lo; i < hi; i++) {
        int d = deg[i];
        offsets[i] = run;
        cursor[i]  = run;
        run += d;
    }
    if (tid == 1023) offsets[N] = run;
}

__global__ void k_scatter(const int* __restrict__ ei, int E, int Et,
                          int* __restrict__ cursor, int* __restrict__ eid) {
    int i = blockIdx.x * blockDim.x + threadIdx.x;
    if (i < Et) {
        int d = (i < E) ? ei[E + i] : (i - E);
        int pos = atomicAdd(&cursor[d], 1);
        eid[pos] = i;
    }
}

// ---------------- Layer 1 GEMM: x[N,128] @ Wl1/Wr1 [128,256] ----------------

__global__ __launch_bounds__(256) void k_gemm1(const float* __restrict__ x,
                                               const float* __restrict__ Wl,
                                               const float* __restrict__ Wr,
                                               float* __restrict__ xl,
                                               float* __restrict__ xr, int N) {
    __shared__ float xs[16][128];
    int row0 = blockIdx.x * 16;
    int tid = threadIdx.x;
    // stage 16 rows of x
    for (int j = 0; j < 8; j++) {
        int idx = j * 256 + tid;
        int r = idx >> 7, c = idx & 127;
        int rr = min(row0 + r, N - 1);
        xs[r][c] = x[(size_t)rr * 128 + c];
    }
    __syncthreads();
    int col = tid;  // 0..255
    float accl[16], accr[16];
#pragma unroll
    for (int r = 0; r < 16; r++) { accl[r] = 0.f; accr[r] = 0.f; }
    for (int k = 0; k < 128; k++) {
        float wl = Wl[k * 256 + col];
        float wr = Wr[k * 256 + col];
#pragma unroll
        for (int r = 0; r < 16; r++) {
            float xv = xs[r][k];   // wave-broadcast, conflict-free
            accl[r] += xv * wl;
            accr[r] += xv * wr;
        }
    }
#pragma unroll
    for (int r = 0; r < 16; r++) {
        int row = row0 + r;
        if (row < N) {
            size_t o = (size_t)row * 256 + col;
            xl[o] = accl[r];
            xr[o] = accr[r];
        }
    }
}

// ---------------- Layer 2 GEMM: h1[N,256] @ Wl2/Wr2 [256,64] ----------------

__global__ __launch_bounds__(256) void k_gemm2(const float* __restrict__ h,
                                               const float* __restrict__ Wl,
                                               const float* __restrict__ Wr,
                                               float* __restrict__ xl,
                                               float* __restrict__ xr, int N) {
    __shared__ float hs[32][257];  // +1 pad: 4 row-groups read stride-8 rows
    int row0 = blockIdx.x * 32;
    int tid = threadIdx.x;
    for (int j = 0; j < 32; j++) {
        int idx = j * 256 + tid;
        int r = idx >> 8, c = idx & 255;
        int rr = min(row0 + r, N - 1);
        hs[r][c] = h[(size_t)rr * 256 + c];
    }
    __syncthreads();
    int col = tid & 63;
    int rg  = tid >> 6;  // 4 groups x 8 rows
    float accl[8], accr[8];
#pragma unroll
    for (int r = 0; r < 8; r++) { accl[r] = 0.f; accr[r] = 0.f; }
    for (int k = 0; k < 256; k++) {
        float wl = Wl[k * 64 + col];
        float wr = Wr[k * 64 + col];
#pragma unroll
        for (int r = 0; r < 8; r++) {
            float hv = hs[rg * 8 + r][k];
            accl[r] += hv * wl;
            accr[r] += hv * wr;
        }
    }
#pragma unroll
    for (int r = 0; r < 8; r++) {
        int row = row0 + rg * 8 + r;
        if (row < N) {
            xl[(size_t)row * 64 + col] = accl[r];
            xr[(size_t)row * 64 + col] = accr[r];
        }
    }
}

// ---------------- Layer 1 edge scores: one wave per edge ----------------

__global__ __launch_bounds__(256) void k_scores1(const int* __restrict__ ei, int E, int Et,
                                                 const float* __restrict__ xl,
                                                 const float* __restrict__ xr,
                                                 const float* __restrict__ att,
                                                 float* __restrict__ scores) {
    int wid  = (blockIdx.x * blockDim.x + threadIdx.x) >> 6;
    int lane = threadIdx.x & 63;
    if (wid >= Et) return;
    int s = (wid < E) ? ei[wid]     : (wid - E);
    int d = (wid < E) ? ei[E + wid] : (wid - E);
    float4 xlv = *(const float4*)(xl + (size_t)s * 256 + lane * 4);
    float4 xrv = *(const float4*)(xr + (size_t)d * 256 + lane * 4);
    float4 av  = *(const float4*)(att + lane * 4);
    float p = lrelu(xlv.x + xrv.x) * av.x + lrelu(xlv.y + xrv.y) * av.y +
              lrelu(xlv.z + xrv.z) * av.z + lrelu(xlv.w + xrv.w) * av.w;
    // reduce within each 8-lane head group
    p += __shfl_xor(p, 1);
    p += __shfl_xor(p, 2);
    p += __shfl_xor(p, 4);
    if ((lane & 7) == 0) scores[(size_t)wid * 8 + (lane >> 3)] = p;
}

// ---------------- Layer 1 gather: one wave per destination node ----------------

__global__ __launch_bounds__(256) void k_gather1(const int* __restrict__ ei, int E, int N,
                                                 const int* __restrict__ offsets,
                                                 const int* __restrict__ eid,
                                                 const float* __restrict__ xl,
                                                 const float* __restrict__ scores,
                                                 const float* __restrict__ b1,
                                                 float* __restrict__ h1) {
    int wid  = (blockIdx.x * blockDim.x + threadIdx.x) >> 6;
    int lane = threadIdx.x & 63;
    if (wid >= N) return;
    int start = offsets[wid], end = offsets[wid + 1];
    int h = lane >> 3;
    float m = -1e30f, ssum = 0.f;
    if (lane < 8) {
        for (int p = start; p < end; p++) {
            int e = eid[p];
            m = fmaxf(m, scores[(size_t)e * 8 + lane]);
        }
        for (int p = start; p < end; p++) {
            int e = eid[p];
            ssum += expf(scores[(size_t)e * 8 + lane] - m);
        }
    }
    float mh  = __shfl(m, h);
    float inv = 1.f / __shfl(ssum, h);
    float4 acc = {0.f, 0.f, 0.f, 0.f};
    for (int p = start; p < end; p++) {
        int e = eid[p];
        int s = (e < E) ? ei[e] : (e - E);
        float alpha = expf(scores[(size_t)e * 8 + h] - mh) * inv;
        float4 v = *(const float4*)(xl + (size_t)s * 256 + lane * 4);
        acc.x += alpha * v.x;
        acc.y += alpha * v.y;
        acc.z += alpha * v.z;
        acc.w += alpha * v.w;
    }
    float4 bv = *(const float4*)(b1 + lane * 4);
    float4 o;
    o.x = elu1(acc.x + bv.x);
    o.y = elu1(acc.y + bv.y);
    o.z = elu1(acc.z + bv.z);
    o.w = elu1(acc.w + bv.w);
    *(float4*)(h1 + (size_t)wid * 256 + lane * 4) = o;
}

// ---------------- Layer 2 edge scores ----------------

__global__ __launch_bounds__(256) void k_scores2(const int* __restrict__ ei, int E, int Et,
                                                 const float* __restrict__ xl,
                                                 const float* __restrict__ xr,
                                                 const float* __restrict__ att,
                                                 float* __restrict__ scores) {
    int wid  = (blockIdx.x * blockDim.x + threadIdx.x) >> 6;
    int lane = threadIdx.x & 63;
    if (wid >= Et) return;
    int s = (wid < E) ? ei[wid]     : (wid - E);
    int d = (wid < E) ? ei[E + wid] : (wid - E);
    float z = xl[(size_t)s * 64 + lane] + xr[(size_t)d * 64 + lane];
    float p = lrelu(z) * att[lane];
#pragma unroll
    for (int ofs = 1; ofs < 64; ofs <<= 1) p += __shfl_xor(p, ofs);
    if (lane == 0) scores[wid] = p;
}

// ---------------- Layer 2 gather (final output) ----------------

__global__ __launch_bounds__(256) void k_gather2(const int* __restrict__ ei, int E, int N,
                                                 const int* __restrict__ offsets,
                                                 const int* __restrict__ eid,
                                                 const float* __restrict__ xl,
                                                 const float* __restrict__ scores,
                                                 const float* __restrict__ b2,
                                                 float* __restrict__ out) {
    int wid  = (blockIdx.x * blockDim.x + threadIdx.x) >> 6;
    int lane = threadIdx.x & 63;
    if (wid >= N) return;
    int start = offsets[wid], end = offsets[wid + 1];
    float m = -1e30f;
    for (int p = start + lane; p < end; p += 64) m = fmaxf(m, scores[eid[p]]);
#pragma unroll
    for (int ofs = 1; ofs < 64; ofs <<= 1) m = fmaxf(m, __shfl_xor(m, ofs));
    float ssum = 0.f, acc = 0.f;
    for (int p = start; p < end; p++) {
        int e = eid[p];
        float a = expf(scores[e] - m);
        ssum += a;
        int s = (e < E) ? ei[e] : (e - E);
        acc += a * xl[(size_t)s * 64 + lane];
    }
    out[(size_t)wid * 64 + lane] = acc / ssum + b2[lane];
}

// ---------------- launch ----------------

extern "C" void kernel_launch(void* const* d_in, const int* in_sizes, int n_in,
                              void* d_out, int out_size, void* d_ws, size_t ws_size,
                              hipStream_t stream) {
    const float* x    = (const float*)d_in[0];
    const int*   ei   = (const int*)d_in[1];
    // d_in[2] edge_type unused by forward
    const float* Wl1  = (const float*)d_in[3];
    const float* Wr1  = (const float*)d_in[4];
    const float* att1 = (const float*)d_in[5];
    const float* b1   = (const float*)d_in[6];
    const float* Wl2  = (const float*)d_in[7];
    const float* Wr2  = (const float*)d_in[8];
    const float* att2 = (const float*)d_in[9];
    const float* b2   = (const float*)d_in[10];
    float* out = (float*)d_out;

    const int N  = in_sizes[0] / 128;  // 50000
    const int E  = in_sizes[1] / 2;    // 800000
    const int Et = E + N;              // with self loops

    // ---- workspace layout (reuse: h1 overlays xr1; layer-2 buffers overlay xl1) ----
    char* ws = (char*)d_ws;
    size_t off = 0;
    auto alloc = [&](size_t bytes) { size_t o = off; off += (bytes + 255) & ~(size_t)255; return o; };
    size_t o_xl1     = alloc((size_t)N * 256 * 4);
    size_t o_xr1     = alloc((size_t)N * 256 * 4);
    size_t o_scores1 = alloc((size_t)Et * 8 * 4);
    size_t o_offsets = alloc((size_t)(N + 1) * 4);
    size_t o_deg     = alloc((size_t)N * 4);
    size_t o_cursor  = alloc((size_t)N * 4);
    size_t o_eid     = alloc((size_t)Et * 4);
    (void)ws_size;

    float* xl1     = (float*)(ws + o_xl1);
    float* xr1     = (float*)(ws + o_xr1);
    float* scores1 = (float*)(ws + o_scores1);
    int*   offsets = (int*)(ws + o_offsets);
    int*   deg     = (int*)(ws + o_deg);
    int*   cursor  = (int*)(ws + o_cursor);
    int*   eid     = (int*)(ws + o_eid);
    // dead-buffer reuse:
    float* h1      = xr1;                                    // written after xr1's last read
    float* xl2     = (float*)(ws + o_xl1);                   // xl1 dead after gather1
    float* xr2     = (float*)(ws + o_xl1 + (size_t)N * 64 * 4);
    float* scores2 = (float*)(ws + o_xl1 + (size_t)N * 128 * 4);

    // ---- CSR build (once; valid for both layers) ----
    hipMemsetAsync(deg, 0, (size_t)N * 4, stream);
    int tb = 256;
    k_hist<<<(Et + tb - 1) / tb, tb, 0, stream>>>(ei, E, Et, deg);
    k_scan<<<1, 1024, 0, stream>>>(deg, N, offsets, cursor);
    k_scatter<<<(Et + tb - 1) / tb, tb, 0, stream>>>(ei, E, Et, cursor, eid);

    // ---- layer 1 ----
    k_gemm1<<<(N + 15) / 16, 256, 0, stream>>>(x, Wl1, Wr1, xl1, xr1, N);
    k_scores1<<<(Et + 3) / 4, 256, 0, stream>>>(ei, E, Et, xl1, xr1, att1, scores1);
    k_gather1<<<(N + 3) / 4, 256, 0, stream>>>(ei, E, N, offsets, eid, xl1, scores1, b1, h1);

    // ---- layer 2 ----
    k_gemm2<<<(N + 31) / 32, 256, 0, stream>>>(h1, Wl2, Wr2, xl2, xr2, N);
    k_scores2<<<(Et + 3) / 4, 256, 0, stream>>>(ei, E, Et, xl2, xr2, att2, scores2);
    k_gather2<<<(N + 3) / 4, 256, 0, stream>>>(ei, E, N, offsets, eid, xl2, scores2, b2, out);
}

// Round 2
// 598.506 us; speedup vs baseline: 1.9383x; 1.9383x over previous
//
#include <hip/hip_runtime.h>
#include <math.h>

#define NEG_SLOPE 0.2f

__device__ __forceinline__ float lrelu(float z) { return z > 0.f ? z : NEG_SLOPE * z; }
__device__ __forceinline__ float elu1(float z)  { return z > 0.f ? z : (__expf(z) - 1.f); }

// ---------------- CSR build (stores SRC node id per edge, segmented by dst) ----------------

__global__ void k_hist(const int* __restrict__ ei, int E, int Et, int* __restrict__ deg) {
    int i = blockIdx.x * blockDim.x + threadIdx.x;
    if (i < Et) {
        int d = (i < E) ? ei[E + i] : (i - E);   // self-loop edges: dst = i - E
        atomicAdd(&deg[d], 1);
    }
}

// single-block exclusive scan over N elements -> offsets[N+1], cursor[N]
__global__ void k_scan(const int* __restrict__ deg, int N,
                       int* __restrict__ offsets, int* __restrict__ cursor) {
    __shared__ int sums[1024];
    int tid = threadIdx.x;
    int chunk = (N + 1023) / 1024;
    int lo = tid * chunk;
    int hi = min(lo + chunk, N);
    int s = 0;
    for (int i = lo; i < hi; i++) s += deg[i];
    sums[tid] = s;
    __syncthreads();
    for (int ofs = 1; ofs < 1024; ofs <<= 1) {
        int v = 0;
        if (tid >= ofs) v = sums[tid - ofs];
        __syncthreads();
        if (tid >= ofs) sums[tid] += v;
        __syncthreads();
    }
    int run = (tid == 0) ? 0 : sums[tid - 1];
    for (int i = lo; i < hi; i++) {
        int d = deg[i];
        offsets[i] = run;
        cursor[i]  = run;
        run += d;
    }
    if (tid == 1023) offsets[N] = run;
}

__global__ void k_scatter(const int* __restrict__ ei, int E, int Et,
                          int* __restrict__ cursor, int* __restrict__ srcs) {
    int i = blockIdx.x * blockDim.x + threadIdx.x;
    if (i < Et) {
        int d = (i < E) ? ei[E + i] : (i - E);
        int s = (i < E) ? ei[i]     : (i - E);
        int pos = atomicAdd(&cursor[d], 1);
        srcs[pos] = s;   // store src directly: kills one indirection in the hot loop
    }
}

// ---------------- Layer 1 GEMM: x[N,128] @ Wl1/Wr1 [128,256] ----------------

__global__ __launch_bounds__(256) void k_gemm1(const float* __restrict__ x,
                                               const float* __restrict__ Wl,
                                               const float* __restrict__ Wr,
                                               float* __restrict__ xl,
                                               float* __restrict__ xr, int N) {
    __shared__ float xs[16][128];
    int row0 = blockIdx.x * 16;
    int tid = threadIdx.x;
    for (int j = 0; j < 8; j++) {
        int idx = j * 256 + tid;
        int r = idx >> 7, c = idx & 127;
        int rr = min(row0 + r, N - 1);
        xs[r][c] = x[(size_t)rr * 128 + c];
    }
    __syncthreads();
    int col = tid;  // 0..255
    float accl[16], accr[16];
#pragma unroll
    for (int r = 0; r < 16; r++) { accl[r] = 0.f; accr[r] = 0.f; }
    for (int k = 0; k < 128; k++) {
        float wl = Wl[k * 256 + col];
        float wr = Wr[k * 256 + col];
#pragma unroll
        for (int r = 0; r < 16; r++) {
            float xv = xs[r][k];   // wave-broadcast, conflict-free
            accl[r] += xv * wl;
            accr[r] += xv * wr;
        }
    }
#pragma unroll
    for (int r = 0; r < 16; r++) {
        int row = row0 + r;
        if (row < N) {
            size_t o = (size_t)row * 256 + col;
            xl[o] = accl[r];
            xr[o] = accr[r];
        }
    }
}

// ---------------- Layer 2 GEMM: h1[N,256] @ Wl2/Wr2 [256,64] ----------------

__global__ __launch_bounds__(256) void k_gemm2(const float* __restrict__ h,
                                               const float* __restrict__ Wl,
                                               const float* __restrict__ Wr,
                                               float* __restrict__ xl,
                                               float* __restrict__ xr, int N) {
    __shared__ float hs[32][257];
    int row0 = blockIdx.x * 32;
    int tid = threadIdx.x;
    for (int j = 0; j < 32; j++) {
        int idx = j * 256 + tid;
        int r = idx >> 8, c = idx & 255;
        int rr = min(row0 + r, N - 1);
        hs[r][c] = h[(size_t)rr * 256 + c];
    }
    __syncthreads();
    int col = tid & 63;
    int rg  = tid >> 6;
    float accl[8], accr[8];
#pragma unroll
    for (int r = 0; r < 8; r++) { accl[r] = 0.f; accr[r] = 0.f; }
    for (int k = 0; k < 256; k++) {
        float wl = Wl[k * 64 + col];
        float wr = Wr[k * 64 + col];
#pragma unroll
        for (int r = 0; r < 8; r++) {
            float hv = hs[rg * 8 + r][k];
            accl[r] += hv * wl;
            accr[r] += hv * wr;
        }
    }
#pragma unroll
    for (int r = 0; r < 8; r++) {
        int row = row0 + rg * 8 + r;
        if (row < N) {
            xl[(size_t)row * 64 + col] = accl[r];
            xr[(size_t)row * 64 + col] = accr[r];
        }
    }
}

// ---------------- Layer 1 fused: scores + online softmax + aggregate, one wave/node ----------------
// Lane layout: head h = lane>>3, lane holds 4 channels (float4) of the 32-ch head slice.
// xr[dst] row is wave-invariant (registers); xl[src] row loaded ONCE per edge and used for
// both the score and the weighted accumulation (flash-style online softmax per 8-lane group).

__global__ __launch_bounds__(256) void k_fused1(const int* __restrict__ srcs, int N,
                                                const int* __restrict__ offsets,
                                                const float* __restrict__ xl,
                                                const float* __restrict__ xr,
                                                const float* __restrict__ att,
                                                const float* __restrict__ b1,
                                                float* __restrict__ h1) {
    int wid  = (blockIdx.x * blockDim.x + threadIdx.x) >> 6;
    int lane = threadIdx.x & 63;
    if (wid >= N) return;
    int start = offsets[wid], end = offsets[wid + 1];

    float4 xrv = *(const float4*)(xr + (size_t)wid * 256 + lane * 4);
    float4 av  = *(const float4*)(att + lane * 4);

    float m = -1e30f, ssum = 0.f;
    float4 acc = {0.f, 0.f, 0.f, 0.f};

    for (int p0 = start; p0 < end; p0 += 64) {
        int cnt = end - p0; if (cnt > 64) cnt = 64;
        int sidx = (lane < cnt) ? srcs[p0 + lane] : 0;   // coalesced batch prefetch
        for (int j = 0; j < cnt; j++) {
            int s = __shfl(sidx, j);
            float4 v = *(const float4*)(xl + (size_t)s * 256 + lane * 4);
            float e = lrelu(v.x + xrv.x) * av.x + lrelu(v.y + xrv.y) * av.y +
                      lrelu(v.z + xrv.z) * av.z + lrelu(v.w + xrv.w) * av.w;
            e += __shfl_xor(e, 1);
            e += __shfl_xor(e, 2);
            e += __shfl_xor(e, 4);          // full head score, uniform within 8-lane group
            float mn = fmaxf(m, e);
            float sc = __expf(m - mn);      // 0 on first edge (m = -1e30)
            float w  = __expf(e - mn);
            ssum = ssum * sc + w;
            acc.x = acc.x * sc + w * v.x;
            acc.y = acc.y * sc + w * v.y;
            acc.z = acc.z * sc + w * v.z;
            acc.w = acc.w * sc + w * v.w;
            m = mn;
        }
    }
    float inv = 1.f / ssum;
    float4 bv = *(const float4*)(b1 + lane * 4);
    float4 o;
    o.x = elu1(acc.x * inv + bv.x);
    o.y = elu1(acc.y * inv + bv.y);
    o.z = elu1(acc.z * inv + bv.z);
    o.w = elu1(acc.w * inv + bv.w);
    *(float4*)(h1 + (size_t)wid * 256 + lane * 4) = o;   // h1 aliases xr: row wid only
}

// ---------------- Layer 2 fused (final output), one wave/node, 1 head x 64 ch ----------------

__global__ __launch_bounds__(256) void k_fused2(const int* __restrict__ srcs, int N,
                                                const int* __restrict__ offsets,
                                                const float* __restrict__ xl,
                                                const float* __restrict__ xr,
                                                const float* __restrict__ att,
                                                const float* __restrict__ b2,
                                                float* __restrict__ out) {
    int wid  = (blockIdx.x * blockDim.x + threadIdx.x) >> 6;
    int lane = threadIdx.x & 63;
    if (wid >= N) return;
    int start = offsets[wid], end = offsets[wid + 1];

    float xrv = xr[(size_t)wid * 64 + lane];
    float av  = att[lane];

    float m = -1e30f, ssum = 0.f, acc = 0.f;

    for (int p0 = start; p0 < end; p0 += 64) {
        int cnt = end - p0; if (cnt > 64) cnt = 64;
        int sidx = (lane < cnt) ? srcs[p0 + lane] : 0;
        for (int j = 0; j < cnt; j++) {
            int s = __shfl(sidx, j);
            float v = xl[(size_t)s * 64 + lane];
            float e = lrelu(v + xrv) * av;
#pragma unroll
            for (int ofs = 1; ofs < 64; ofs <<= 1) e += __shfl_xor(e, ofs);
            float mn = fmaxf(m, e);
            float sc = __expf(m - mn);
            float w  = __expf(e - mn);
            ssum = ssum * sc + w;
            acc  = acc * sc + w * v;
            m = mn;
        }
    }
    out[(size_t)wid * 64 + lane] = acc / ssum + b2[lane];
}

// ---------------- launch ----------------

extern "C" void kernel_launch(void* const* d_in, const int* in_sizes, int n_in,
                              void* d_out, int out_size, void* d_ws, size_t ws_size,
                              hipStream_t stream) {
    const float* x    = (const float*)d_in[0];
    const int*   ei   = (const int*)d_in[1];
    // d_in[2] edge_type unused by forward
    const float* Wl1  = (const float*)d_in[3];
    const float* Wr1  = (const float*)d_in[4];
    const float* att1 = (const float*)d_in[5];
    const float* b1   = (const float*)d_in[6];
    const float* Wl2  = (const float*)d_in[7];
    const float* Wr2  = (const float*)d_in[8];
    const float* att2 = (const float*)d_in[9];
    const float* b2   = (const float*)d_in[10];
    float* out = (float*)d_out;

    const int N  = in_sizes[0] / 128;  // 50000
    const int E  = in_sizes[1] / 2;    // 800000
    const int Et = E + N;              // with self loops

    // ---- workspace layout ----
    char* ws = (char*)d_ws;
    size_t off = 0;
    auto alloc = [&](size_t bytes) { size_t o = off; off += (bytes + 255) & ~(size_t)255; return o; };
    size_t o_xl1     = alloc((size_t)N * 256 * 4);
    size_t o_xr1     = alloc((size_t)N * 256 * 4);
    size_t o_offsets = alloc((size_t)(N + 1) * 4);
    size_t o_deg     = alloc((size_t)N * 4);
    size_t o_cursor  = alloc((size_t)N * 4);
    size_t o_srcs    = alloc((size_t)Et * 4);
    (void)ws_size;

    float* xl1     = (float*)(ws + o_xl1);
    float* xr1     = (float*)(ws + o_xr1);
    int*   offsets = (int*)(ws + o_offsets);
    int*   deg     = (int*)(ws + o_deg);
    int*   cursor  = (int*)(ws + o_cursor);
    int*   srcs    = (int*)(ws + o_srcs);
    // dead-buffer reuse:
    float* h1  = xr1;                                      // in-place: wave wid reads xr1[wid] then writes h1[wid]
    float* xl2 = (float*)(ws + o_xl1);                     // xl1 dead after fused1
    float* xr2 = (float*)(ws + o_xl1 + (size_t)N * 64 * 4);

    // ---- CSR build (once; valid for both layers) ----
    hipMemsetAsync(deg, 0, (size_t)N * 4, stream);
    int tb = 256;
    k_hist<<<(Et + tb - 1) / tb, tb, 0, stream>>>(ei, E, Et, deg);
    k_scan<<<1, 1024, 0, stream>>>(deg, N, offsets, cursor);
    k_scatter<<<(Et + tb - 1) / tb, tb, 0, stream>>>(ei, E, Et, cursor, srcs);

    // ---- layer 1 ----
    k_gemm1<<<(N + 15) / 16, 256, 0, stream>>>(x, Wl1, Wr1, xl1, xr1, N);
    k_fused1<<<(N + 3) / 4, 256, 0, stream>>>(srcs, N, offsets, xl1, xr1, att1, b1, h1);

    // ---- layer 2 ----
    k_gemm2<<<(N + 31) / 32, 256, 0, stream>>>(h1, Wl2, Wr2, xl2, xr2, N);
    k_fused2<<<(N + 3) / 4, 256, 0, stream>>>(srcs, N, offsets, xl2, xr2, att2, b2, out);
}